// Round 1
// baseline (883.760 us; speedup 1.0000x reference)
//
#include <hip/hip_runtime.h>

// v7: v6 + async-STAGE split (T14). v6's K/V tile staging sat entirely between
// the two block barriers: global load (L2 ~200-400cy) + split_bf16 + ds_write
// all on the barrier-to-barrier critical path, 64x per block. v7 issues tile
// t+1's global loads into registers during tile t's compute phase (~1600cy of
// threefry/MFMA), so staging starts with data already in regs.
// Requires raw s_barrier + manual lgkmcnt waits: HIP __syncthreads() drains
// vmcnt(0) before s_barrier, which would kill the in-flight prefetch.
// Compute phase / mask math / LDS layout identical to harness-verified v6.

#define S_LEN 2048
#define D_DIM 64
#define KT    32
#define QT    16
#define NWAVE 4
#define KSTR  72   // K row stride (shorts): b128 frag reads 2-way (free)
#define VROW  66   // V row-major stride (shorts): scalar u16 reads conflict-free
#define PSTR  40   // P row stride (shorts): b128 reads conflict-optimal

typedef short  short8  __attribute__((ext_vector_type(8)));
typedef float  floatx4 __attribute__((ext_vector_type(4)));

__device__ __forceinline__ unsigned rotl(unsigned x, int r) {
  return __builtin_amdgcn_alignbit(x, x, 32 - r);   // 1x v_alignbit_b32
}

// Partitionable threefry2x32, key (0,42), counter (0, i):
// random word w = x0 ^ x1; keep(i) <=> bit31(w) == 0.
// Returns all-ones if DROP, 0 if keep (mask for the bf16 pack).
__device__ __forceinline__ unsigned drop_mask(unsigned i) {
  const unsigned KS1 = 42u;
  const unsigned KS2 = 0x1BD11BDAu ^ 42u;
  unsigned a = 0u;
  unsigned b = i + KS1;
#define TFR(r) { a += b; b = rotl(b, r); b ^= a; }
  TFR(13) TFR(15) TFR(26) TFR(6)   a += KS1; b += KS2 + 1u;
  TFR(17) TFR(29) TFR(16) TFR(24)  a += KS2; b += 2u;
  TFR(13) TFR(15) TFR(26) TFR(6)             b += KS1 + 3u;
  TFR(17) TFR(29) TFR(16) TFR(24)  a += KS1; b += KS2 + 4u;
  TFR(13) TFR(15) TFR(26) TFR(6)   a += KS2; b += 5u;
#undef TFR
  return (unsigned)(((int)(a ^ b)) >> 31);   // sign-extend bit31
}

__device__ __forceinline__ void split_bf16(float x, unsigned short& h, unsigned short& l) {
  unsigned u = __float_as_uint(x);
  h = (unsigned short)(u >> 16);
  float r = x - __uint_as_float(u & 0xFFFF0000u);
  l = (unsigned short)(__float_as_uint(r) >> 16);
}

#define MFMA(a, b, c) __builtin_amdgcn_mfma_f32_16x16x32_bf16((a), (b), (c), 0, 0, 0)

__global__ __launch_bounds__(256, 6) void attn_fused_v7(
    const float* __restrict__ Qg, const float* __restrict__ Kg,
    const float* __restrict__ Vg, float* __restrict__ Og) {

  __shared__ __attribute__((aligned(16))) unsigned short Kh[KT * KSTR];
  __shared__ __attribute__((aligned(16))) unsigned short Kl[KT * KSTR];
  __shared__ __attribute__((aligned(16))) unsigned short Vs[KT * VROW];
  __shared__ __attribute__((aligned(16))) unsigned short Ph[NWAVE][QT * PSTR];

  const int tid  = threadIdx.x;
  const int wave = tid >> 6;
  const int lane = tid & 63;
  const int m16  = lane & 15;
  const int quad = lane >> 4;

  const int bh    = blockIdx.x >> 5;   // 64 (b,h) heads
  const int qtile = blockIdx.x & 31;   // 32 q-tiles of 64 rows
  const int q0    = qtile * (QT * NWAVE) + wave * QT;
  const size_t head_off = (size_t)bh * S_LEN * D_DIM;

  // Q A-fragments (hi/lo split): A[m=m16][k = kc*32 + quad*8 + j]
  short8 qh[2], ql[2];
#pragma unroll
  for (int kc = 0; kc < 2; ++kc) {
    const float* qp = Qg + head_off + (size_t)(q0 + m16) * D_DIM + kc * 32 + quad * 8;
    floatx4 f0 = *(const floatx4*)qp;
    floatx4 f1 = *(const floatx4*)(qp + 4);
#pragma unroll
    for (int e = 0; e < 4; ++e) {
      unsigned short h, l;
      split_bf16(f0[e], h, l);
      qh[kc][e] = (short)h;  ql[kc][e] = (short)l;
      split_bf16(f1[e], h, l);
      qh[kc][4 + e] = (short)h;  ql[kc][4 + e] = (short)l;
    }
  }

  floatx4 o_acc[4];
#pragma unroll
  for (int n = 0; n < 4; ++n) o_acc[n] = (floatx4){0.f, 0.f, 0.f, 0.f};
  float lsum[4];
#pragma unroll
  for (int r = 0; r < 4; ++r) lsum[r] = 0.f;

  // flat mask index: i = (bh*2048 + q)*2048 + k; q = q0+quad*4+r, k = kb+nb*16+m16
  const unsigned ibase0 =
      ((unsigned)(bh * S_LEN + q0 + quad * 4)) * (unsigned)S_LEN + (unsigned)m16;

  // ---- staging geometry: this thread owns rows srow and srow+16, cols sc4..sc4+3
  const int srow = tid >> 4;            // 0..15
  const int sc4  = (tid & 15) << 2;     // 0..60 step 4
  const float* kbase = Kg + head_off + (size_t)srow * D_DIM + sc4;
  const float* vbase = Vg + head_off + (size_t)srow * D_DIM + sc4;

  // prologue prefetch: tile kb=0 into registers
  floatx4 kpre0 = *(const floatx4*)(kbase);
  floatx4 kpre1 = *(const floatx4*)(kbase + 16 * D_DIM);
  floatx4 vpre0 = *(const floatx4*)(vbase);
  floatx4 vpre1 = *(const floatx4*)(vbase + 16 * D_DIM);

  for (int kb = 0; kb < S_LEN; kb += KT) {
    // all waves' LDS reads from the previous tile are complete
    asm volatile("s_waitcnt lgkmcnt(0)" ::: "memory");
    __builtin_amdgcn_s_barrier();

    // ---- write the prefetched K (hi+lo) and V (hi, row-major) tile into LDS.
    // vmcnt wait for the prefetch folds into the first split use (compute of
    // the previous tile ran while the loads were in flight -> wait ~0).
#pragma unroll
    for (int half = 0; half < 2; ++half) {
      floatx4 kv = half ? kpre1 : kpre0;
      floatx4 vv = half ? vpre1 : vpre0;
      int row = srow + half * 16;
      unsigned short h0, h1, h2, h3, l0, l1, l2, l3;
      split_bf16(kv[0], h0, l0); split_bf16(kv[1], h1, l1);
      split_bf16(kv[2], h2, l2); split_bf16(kv[3], h3, l3);
      int kidx = row * KSTR + sc4;
      *(unsigned*)&Kh[kidx]     = (unsigned)h0 | ((unsigned)h1 << 16);
      *(unsigned*)&Kh[kidx + 2] = (unsigned)h2 | ((unsigned)h3 << 16);
      *(unsigned*)&Kl[kidx]     = (unsigned)l0 | ((unsigned)l1 << 16);
      *(unsigned*)&Kl[kidx + 2] = (unsigned)l2 | ((unsigned)l3 << 16);
      unsigned v01 = (__float_as_uint(vv[0]) >> 16) |
                     (__float_as_uint(vv[1]) & 0xFFFF0000u);
      unsigned v23 = (__float_as_uint(vv[2]) >> 16) |
                     (__float_as_uint(vv[3]) & 0xFFFF0000u);
      int vidx = row * VROW + sc4;
      *(unsigned*)&Vs[vidx]     = v01;
      *(unsigned*)&Vs[vidx + 2] = v23;
    }

    // ---- issue NEXT tile's global loads; they stay in flight across the
    // barrier below (raw s_barrier: no vmcnt drain) and complete during the
    // ~1600cy compute phase.
    if (kb + KT < S_LEN) {
      const float* kp = kbase + (size_t)(kb + KT) * D_DIM;
      const float* vp = vbase + (size_t)(kb + KT) * D_DIM;
      kpre0 = *(const floatx4*)(kp);
      kpre1 = *(const floatx4*)(kp + 16 * D_DIM);
      vpre0 = *(const floatx4*)(vp);
      vpre1 = *(const floatx4*)(vp + 16 * D_DIM);
    }

    // ds_writes visible to the whole block; deliberately NOT draining vmcnt
    asm volatile("s_waitcnt lgkmcnt(0)" ::: "memory");
    __builtin_amdgcn_s_barrier();

    // ---- S = Q K^T (split-bf16 3-term: hh + hl + lh)
    floatx4 sc[2];
#pragma unroll
    for (int nb = 0; nb < 2; ++nb) {
      floatx4 acc = (floatx4){0.f, 0.f, 0.f, 0.f};
#pragma unroll
      for (int kc = 0; kc < 2; ++kc) {
        int bidx = (nb * 16 + m16) * KSTR + kc * 32 + quad * 8;
        short8 kbh = *(const short8*)&Kh[bidx];
        short8 kbl = *(const short8*)&Kl[bidx];
        acc = MFMA(qh[kc], kbh, acc);
        acc = MFMA(qh[kc], kbl, acc);
        acc = MFMA(ql[kc], kbh, acc);
      }
      sc[nb] = acc;
    }

    // ---- p = exp(s) (|s| <~ 50: no overflow), per-lane l partial,
    //      exact threefry mask, P(hi bf16, masked) -> LDS
#pragma unroll
    for (int nb = 0; nb < 2; ++nb)
#pragma unroll
      for (int r = 0; r < 4; ++r) {
        float pe = __expf(sc[nb][r]);
        lsum[r] += pe;
        unsigned i = ibase0 + (unsigned)kb + (unsigned)(r * S_LEN) + (unsigned)(nb * 16);
        unsigned hbits = (__float_as_uint(pe) >> 16) & ~drop_mask(i);
        Ph[wave][(quad * 4 + r) * PSTR + nb * 16 + m16] = (unsigned short)hbits;
      }
    // Ph is wave-private; same-wave LDS RAW handled by lgkmcnt.

    // ---- O += P V  (P hi x V hi); V B-frag via conflict-free scalar u16
    short8 pa = *(const short8*)&Ph[wave][m16 * PSTR + quad * 8];
#pragma unroll
    for (int n = 0; n < 4; ++n) {
      short8 vb;
#pragma unroll
      for (int j = 0; j < 8; ++j)
        vb[j] = (short)Vs[(quad * 8 + j) * VROW + n * 16 + m16];
      o_acc[n] = MFMA(pa, vb, o_acc[n]);
    }
  }

  // ---- final l reduction over the 16 m16 lanes
#pragma unroll
  for (int off = 8; off >= 1; off >>= 1)
#pragma unroll
    for (int r = 0; r < 4; ++r)
      lsum[r] += __shfl_xor(lsum[r], off, 64);

  // ---- epilogue: out = O * (2 / l)   (2 = 1/(1-p) dropout scale)
#pragma unroll
  for (int r = 0; r < 4; ++r) {
    float scale = 2.0f / lsum[r];
#pragma unroll
    for (int n = 0; n < 4; ++n) {
      Og[head_off + (size_t)(q0 + quad * 4 + r) * D_DIM + n * 16 + m16] =
          o_acc[n][r] * scale;
    }
  }
}

extern "C" void kernel_launch(void* const* d_in, const int* in_sizes, int n_in,
                              void* d_out, int out_size, void* d_ws, size_t ws_size,
                              hipStream_t stream) {
  (void)in_sizes; (void)n_in; (void)out_size; (void)d_ws; (void)ws_size;
  const float* Q = (const float*)d_in[0];
  const float* K = (const float*)d_in[1];
  const float* V = (const float*)d_in[2];
  float* O = (float*)d_out;
  hipLaunchKernelGGL(attn_fused_v7, dim3(2048), dim3(256), 0, stream, Q, K, V, O);
}

// Round 2
// 856.652 us; speedup vs baseline: 1.0316x; 1.0316x over previous
//
#include <hip/hip_runtime.h>

// v8: v7 + register-allocation fix. v7's __launch_bounds__(256,6) only sets a
// MINIMUM waves/EU; the allocator squeezed to VGPR_Count=40 (chasing the
// 8-waves/EU tier at <=64 regs) with ~60 VGPRs of live state -> remat/AGPR-
// shuffle inflation of the threefry loop (~2.2x VALU instr fat, measured 227
// lane-instr/element vs ~100 clean). amdgpu_waves_per_eu(4,4) pins min=max=4
// -> 128-reg budget, no squeeze incentive. Occupancy was 51% anyway.
// T14 async prefetch + raw s_barrier structure unchanged from v7 (verified).

#define S_LEN 2048
#define D_DIM 64
#define KT    32
#define QT    16
#define NWAVE 4
#define KSTR  72   // K row stride (shorts): b128 frag reads 2-way (free)
#define VROW  66   // V row-major stride (shorts): scalar u16 reads conflict-free
#define PSTR  40   // P row stride (shorts): b128 reads conflict-optimal

typedef short  short8  __attribute__((ext_vector_type(8)));
typedef float  floatx4 __attribute__((ext_vector_type(4)));

__device__ __forceinline__ unsigned rotl(unsigned x, int r) {
  return __builtin_amdgcn_alignbit(x, x, 32 - r);   // 1x v_alignbit_b32
}

// Partitionable threefry2x32, key (0,42), counter (0, i):
// random word w = x0 ^ x1; keep(i) <=> bit31(w) == 0.
// Returns all-ones if DROP, 0 if keep (mask for the bf16 pack).
__device__ __forceinline__ unsigned drop_mask(unsigned i) {
  const unsigned KS1 = 42u;
  const unsigned KS2 = 0x1BD11BDAu ^ 42u;
  unsigned a = 0u;
  unsigned b = i + KS1;
#define TFR(r) { a += b; b = rotl(b, r); b ^= a; }
  TFR(13) TFR(15) TFR(26) TFR(6)   a += KS1; b += KS2 + 1u;
  TFR(17) TFR(29) TFR(16) TFR(24)  a += KS2; b += 2u;
  TFR(13) TFR(15) TFR(26) TFR(6)             b += KS1 + 3u;
  TFR(17) TFR(29) TFR(16) TFR(24)  a += KS1; b += KS2 + 4u;
  TFR(13) TFR(15) TFR(26) TFR(6)   a += KS2; b += 5u;
#undef TFR
  return (unsigned)(((int)(a ^ b)) >> 31);   // sign-extend bit31
}

__device__ __forceinline__ void split_bf16(float x, unsigned short& h, unsigned short& l) {
  unsigned u = __float_as_uint(x);
  h = (unsigned short)(u >> 16);
  float r = x - __uint_as_float(u & 0xFFFF0000u);
  l = (unsigned short)(__float_as_uint(r) >> 16);
}

#define MFMA(a, b, c) __builtin_amdgcn_mfma_f32_16x16x32_bf16((a), (b), (c), 0, 0, 0)

__global__ __launch_bounds__(256)
__attribute__((amdgpu_waves_per_eu(4, 4)))
void attn_fused_v8(
    const float* __restrict__ Qg, const float* __restrict__ Kg,
    const float* __restrict__ Vg, float* __restrict__ Og) {

  __shared__ __attribute__((aligned(16))) unsigned short Kh[KT * KSTR];
  __shared__ __attribute__((aligned(16))) unsigned short Kl[KT * KSTR];
  __shared__ __attribute__((aligned(16))) unsigned short Vs[KT * VROW];
  __shared__ __attribute__((aligned(16))) unsigned short Ph[NWAVE][QT * PSTR];

  const int tid  = threadIdx.x;
  const int wave = tid >> 6;
  const int lane = tid & 63;
  const int m16  = lane & 15;
  const int quad = lane >> 4;

  const int bh    = blockIdx.x >> 5;   // 64 (b,h) heads
  const int qtile = blockIdx.x & 31;   // 32 q-tiles of 64 rows
  const int q0    = qtile * (QT * NWAVE) + wave * QT;
  const size_t head_off = (size_t)bh * S_LEN * D_DIM;

  // Q A-fragments (hi/lo split): A[m=m16][k = kc*32 + quad*8 + j]
  short8 qh[2], ql[2];
#pragma unroll
  for (int kc = 0; kc < 2; ++kc) {
    const float* qp = Qg + head_off + (size_t)(q0 + m16) * D_DIM + kc * 32 + quad * 8;
    floatx4 f0 = *(const floatx4*)qp;
    floatx4 f1 = *(const floatx4*)(qp + 4);
#pragma unroll
    for (int e = 0; e < 4; ++e) {
      unsigned short h, l;
      split_bf16(f0[e], h, l);
      qh[kc][e] = (short)h;  ql[kc][e] = (short)l;
      split_bf16(f1[e], h, l);
      qh[kc][4 + e] = (short)h;  ql[kc][4 + e] = (short)l;
    }
  }

  floatx4 o_acc[4];
#pragma unroll
  for (int n = 0; n < 4; ++n) o_acc[n] = (floatx4){0.f, 0.f, 0.f, 0.f};
  float lsum[4];
#pragma unroll
  for (int r = 0; r < 4; ++r) lsum[r] = 0.f;

  // flat mask index: i = (bh*2048 + q)*2048 + k; q = q0+quad*4+r, k = kb+nb*16+m16
  const unsigned ibase0 =
      ((unsigned)(bh * S_LEN + q0 + quad * 4)) * (unsigned)S_LEN + (unsigned)m16;

  // ---- staging geometry: this thread owns rows srow and srow+16, cols sc4..sc4+3
  const int srow = tid >> 4;            // 0..15
  const int sc4  = (tid & 15) << 2;     // 0..60 step 4
  const float* kbase = Kg + head_off + (size_t)srow * D_DIM + sc4;
  const float* vbase = Vg + head_off + (size_t)srow * D_DIM + sc4;

  // prologue prefetch: tile kb=0 into registers
  floatx4 kpre0 = *(const floatx4*)(kbase);
  floatx4 kpre1 = *(const floatx4*)(kbase + 16 * D_DIM);
  floatx4 vpre0 = *(const floatx4*)(vbase);
  floatx4 vpre1 = *(const floatx4*)(vbase + 16 * D_DIM);

  for (int kb = 0; kb < S_LEN; kb += KT) {
    // all waves' LDS reads from the previous tile are complete
    asm volatile("s_waitcnt lgkmcnt(0)" ::: "memory");
    __builtin_amdgcn_s_barrier();

    // ---- write the prefetched K (hi+lo) and V (hi, row-major) tile into LDS.
    // vmcnt wait for the prefetch folds into the first split use (compute of
    // the previous tile ran while the loads were in flight -> wait ~0).
#pragma unroll
    for (int half = 0; half < 2; ++half) {
      floatx4 kv = half ? kpre1 : kpre0;
      floatx4 vv = half ? vpre1 : vpre0;
      int row = srow + half * 16;
      unsigned short h0, h1, h2, h3, l0, l1, l2, l3;
      split_bf16(kv[0], h0, l0); split_bf16(kv[1], h1, l1);
      split_bf16(kv[2], h2, l2); split_bf16(kv[3], h3, l3);
      int kidx = row * KSTR + sc4;
      *(unsigned*)&Kh[kidx]     = (unsigned)h0 | ((unsigned)h1 << 16);
      *(unsigned*)&Kh[kidx + 2] = (unsigned)h2 | ((unsigned)h3 << 16);
      *(unsigned*)&Kl[kidx]     = (unsigned)l0 | ((unsigned)l1 << 16);
      *(unsigned*)&Kl[kidx + 2] = (unsigned)l2 | ((unsigned)l3 << 16);
      unsigned v01 = (__float_as_uint(vv[0]) >> 16) |
                     (__float_as_uint(vv[1]) & 0xFFFF0000u);
      unsigned v23 = (__float_as_uint(vv[2]) >> 16) |
                     (__float_as_uint(vv[3]) & 0xFFFF0000u);
      int vidx = row * VROW + sc4;
      *(unsigned*)&Vs[vidx]     = v01;
      *(unsigned*)&Vs[vidx + 2] = v23;
    }

    // ---- issue NEXT tile's global loads; they stay in flight across the
    // barrier below (raw s_barrier: no vmcnt drain) and complete during the
    // ~1600cy compute phase.
    if (kb + KT < S_LEN) {
      const float* kp = kbase + (size_t)(kb + KT) * D_DIM;
      const float* vp = vbase + (size_t)(kb + KT) * D_DIM;
      kpre0 = *(const floatx4*)(kp);
      kpre1 = *(const floatx4*)(kp + 16 * D_DIM);
      vpre0 = *(const floatx4*)(vp);
      vpre1 = *(const floatx4*)(vp + 16 * D_DIM);
    }

    // ds_writes visible to the whole block; deliberately NOT draining vmcnt
    asm volatile("s_waitcnt lgkmcnt(0)" ::: "memory");
    __builtin_amdgcn_s_barrier();

    // ---- S = Q K^T (split-bf16 3-term: hh + hl + lh)
    floatx4 sc[2];
#pragma unroll
    for (int nb = 0; nb < 2; ++nb) {
      floatx4 acc = (floatx4){0.f, 0.f, 0.f, 0.f};
#pragma unroll
      for (int kc = 0; kc < 2; ++kc) {
        int bidx = (nb * 16 + m16) * KSTR + kc * 32 + quad * 8;
        short8 kbh = *(const short8*)&Kh[bidx];
        short8 kbl = *(const short8*)&Kl[bidx];
        acc = MFMA(qh[kc], kbh, acc);
        acc = MFMA(qh[kc], kbl, acc);
        acc = MFMA(ql[kc], kbh, acc);
      }
      sc[nb] = acc;
    }

    // ---- p = exp(s) (|s| <~ 50: no overflow), per-lane l partial,
    //      exact threefry mask, P(hi bf16, masked) -> LDS
#pragma unroll
    for (int nb = 0; nb < 2; ++nb)
#pragma unroll
      for (int r = 0; r < 4; ++r) {
        float pe = __expf(sc[nb][r]);
        lsum[r] += pe;
        unsigned i = ibase0 + (unsigned)kb + (unsigned)(r * S_LEN) + (unsigned)(nb * 16);
        unsigned hbits = (__float_as_uint(pe) >> 16) & ~drop_mask(i);
        Ph[wave][(quad * 4 + r) * PSTR + nb * 16 + m16] = (unsigned short)hbits;
      }
    // Ph is wave-private; same-wave LDS RAW handled by lgkmcnt.

    // ---- O += P V  (P hi x V hi); V B-frag via conflict-free scalar u16
    short8 pa = *(const short8*)&Ph[wave][m16 * PSTR + quad * 8];
#pragma unroll
    for (int n = 0; n < 4; ++n) {
      short8 vb;
#pragma unroll
      for (int j = 0; j < 8; ++j)
        vb[j] = (short)Vs[(quad * 8 + j) * VROW + n * 16 + m16];
      o_acc[n] = MFMA(pa, vb, o_acc[n]);
    }
  }

  // ---- final l reduction over the 16 m16 lanes
#pragma unroll
  for (int off = 8; off >= 1; off >>= 1)
#pragma unroll
    for (int r = 0; r < 4; ++r)
      lsum[r] += __shfl_xor(lsum[r], off, 64);

  // ---- epilogue: out = O * (2 / l)   (2 = 1/(1-p) dropout scale)
#pragma unroll
  for (int r = 0; r < 4; ++r) {
    float scale = 2.0f / lsum[r];
#pragma unroll
    for (int n = 0; n < 4; ++n) {
      Og[head_off + (size_t)(q0 + quad * 4 + r) * D_DIM + n * 16 + m16] =
          o_acc[n][r] * scale;
    }
  }
}

extern "C" void kernel_launch(void* const* d_in, const int* in_sizes, int n_in,
                              void* d_out, int out_size, void* d_ws, size_t ws_size,
                              hipStream_t stream) {
  (void)in_sizes; (void)n_in; (void)out_size; (void)d_ws; (void)ws_size;
  const float* Q = (const float*)d_in[0];
  const float* K = (const float*)d_in[1];
  const float* V = (const float*)d_in[2];
  float* O = (float*)d_out;
  hipLaunchKernelGGL(attn_fused_v8, dim3(2048), dim3(256), 0, stream, Q, K, V, O);
}

// Round 4
// 796.466 us; speedup vs baseline: 1.1096x; 1.0756x over previous
//
#include <hip/hip_runtime.h>

// v9b: resubmit of v9 (round-3 bench died in infra: "container failed twice").
// Two-kernel split. v6-v8 evidence: monolith is VALU-bound (VALUBusy 91%,
// MfmaUtil 7%) at ~229 lane-instr per mask element vs ~85 clean — the 8-way
// unrolled threefry block (560 instrs) under ~60 live VGPRs gets fat codegen
// regardless of launch-bounds/waves_per_eu hints (40 VGPR @883us, 56 @857us).
// Fix: dedicated maskgen kernel (zero live state, ~20 VGPR, clean ~70
// instr/element, 239us chip VALU floor) writes a bit-packed mask (32MB) to
// d_ws; attn kernel reads 1 u32 per (row, 32-k-block) — per-element cost
// drops 77 -> ~8 VALU. Fallback to monolith if ws_size < 32MB.

#define S_LEN 2048
#define D_DIM 64
#define KT    32
#define QT    16
#define NWAVE 4
#define KSTR  72   // K row stride (shorts): b128 frag reads 2-way (free)
#define VROW  66   // V row-major stride (shorts): scalar u16 reads conflict-free
#define PSTR  40   // P row stride (shorts): b128 reads conflict-optimal
#define MROW  (S_LEN / 32)   // mask words per q-row

typedef short  short8  __attribute__((ext_vector_type(8)));
typedef float  floatx4 __attribute__((ext_vector_type(4)));

__device__ __forceinline__ unsigned rotl(unsigned x, int r) {
  return __builtin_amdgcn_alignbit(x, x, 32 - r);   // 1x v_alignbit_b32
}

// Partitionable threefry2x32, key (0,42), counter (0, i):
// random word w = x0 ^ x1; keep(i) <=> bit31(w) == 0.
// Returns all-ones if DROP, 0 if keep.
__device__ __forceinline__ unsigned drop_mask(unsigned i) {
  const unsigned KS1 = 42u;
  const unsigned KS2 = 0x1BD11BDAu ^ 42u;
  unsigned a = 0u;
  unsigned b = i + KS1;
#define TFR(r) { a += b; b = rotl(b, r); b ^= a; }
  TFR(13) TFR(15) TFR(26) TFR(6)   a += KS1; b += KS2 + 1u;
  TFR(17) TFR(29) TFR(16) TFR(24)  a += KS2; b += 2u;
  TFR(13) TFR(15) TFR(26) TFR(6)             b += KS1 + 3u;
  TFR(17) TFR(29) TFR(16) TFR(24)  a += KS1; b += KS2 + 4u;
  TFR(13) TFR(15) TFR(26) TFR(6)   a += KS2; b += 5u;
#undef TFR
  return (unsigned)(((int)(a ^ b)) >> 31);   // sign-extend bit31
}

// ---- kernel 1: bit-packed dropout mask. word wid covers flat elements
// [wid*32, wid*32+32); bit j == 1 means DROP. One thread per word: 32
// independent 70-op threefry chains, ~6 live VGPRs -> clean codegen, full
// occupancy, VALU-saturated.
__global__ __launch_bounds__(512) void maskgen(unsigned* __restrict__ Mg,
                                               unsigned n_words) {
  unsigned wid = blockIdx.x * 512u + threadIdx.x;
  if (wid >= n_words) return;
  unsigned base = wid << 5;
  unsigned w = 0u;
#pragma unroll
  for (int j = 0; j < 32; ++j)
    w |= drop_mask(base + (unsigned)j) & (1u << j);
  Mg[wid] = w;
}

__device__ __forceinline__ void split_bf16(float x, unsigned short& h, unsigned short& l) {
  unsigned u = __float_as_uint(x);
  h = (unsigned short)(u >> 16);
  float r = x - __uint_as_float(u & 0xFFFF0000u);
  l = (unsigned short)(__float_as_uint(r) >> 16);
}

#define MFMA(a, b, c) __builtin_amdgcn_mfma_f32_16x16x32_bf16((a), (b), (c), 0, 0, 0)

// ---- kernel 2: fused attention. USE_MASK=true reads the precomputed bit
// mask; false inlines threefry (fallback when ws too small — the verified v8
// path).
template <bool USE_MASK>
__global__ __launch_bounds__(256)
__attribute__((amdgpu_waves_per_eu(4, 8)))
void attn_fused(
    const float* __restrict__ Qg, const float* __restrict__ Kg,
    const float* __restrict__ Vg, float* __restrict__ Og,
    const unsigned* __restrict__ Mask) {

  __shared__ __attribute__((aligned(16))) unsigned short Kh[KT * KSTR];
  __shared__ __attribute__((aligned(16))) unsigned short Kl[KT * KSTR];
  __shared__ __attribute__((aligned(16))) unsigned short Vs[KT * VROW];
  __shared__ __attribute__((aligned(16))) unsigned short Ph[NWAVE][QT * PSTR];

  const int tid  = threadIdx.x;
  const int wave = tid >> 6;
  const int lane = tid & 63;
  const int m16  = lane & 15;
  const int quad = lane >> 4;

  const int bh    = blockIdx.x >> 5;   // 64 (b,h) heads
  const int qtile = blockIdx.x & 31;   // 32 q-tiles of 64 rows
  const int q0    = qtile * (QT * NWAVE) + wave * QT;
  const size_t head_off = (size_t)bh * S_LEN * D_DIM;

  // Q A-fragments (hi/lo split): A[m=m16][k = kc*32 + quad*8 + j]
  short8 qh[2], ql[2];
#pragma unroll
  for (int kc = 0; kc < 2; ++kc) {
    const float* qp = Qg + head_off + (size_t)(q0 + m16) * D_DIM + kc * 32 + quad * 8;
    floatx4 f0 = *(const floatx4*)qp;
    floatx4 f1 = *(const floatx4*)(qp + 4);
#pragma unroll
    for (int e = 0; e < 4; ++e) {
      unsigned short h, l;
      split_bf16(f0[e], h, l);
      qh[kc][e] = (short)h;  ql[kc][e] = (short)l;
      split_bf16(f1[e], h, l);
      qh[kc][4 + e] = (short)h;  ql[kc][4 + e] = (short)l;
    }
  }

  floatx4 o_acc[4];
#pragma unroll
  for (int n = 0; n < 4; ++n) o_acc[n] = (floatx4){0.f, 0.f, 0.f, 0.f};
  float lsum[4];
#pragma unroll
  for (int r = 0; r < 4; ++r) lsum[r] = 0.f;

  // flat mask index (fallback path): i = (bh*2048+q)*2048 + k
  const unsigned ibase0 =
      ((unsigned)(bh * S_LEN + q0 + quad * 4)) * (unsigned)S_LEN + (unsigned)m16;
  // mask-word base (mask path): word (row, kb/32) = Mask[row*MROW + kb/32]
  const unsigned mbase = (unsigned)(bh * S_LEN + q0 + quad * 4) * (unsigned)MROW;

  // ---- staging geometry: this thread owns rows srow and srow+16, cols sc4..sc4+3
  const int srow = tid >> 4;            // 0..15
  const int sc4  = (tid & 15) << 2;     // 0..60 step 4
  const float* kbase = Kg + head_off + (size_t)srow * D_DIM + sc4;
  const float* vbase = Vg + head_off + (size_t)srow * D_DIM + sc4;

  // prologue prefetch: tile kb=0 into registers
  floatx4 kpre0 = *(const floatx4*)(kbase);
  floatx4 kpre1 = *(const floatx4*)(kbase + 16 * D_DIM);
  floatx4 vpre0 = *(const floatx4*)(vbase);
  floatx4 vpre1 = *(const floatx4*)(vbase + 16 * D_DIM);

  for (int kb = 0; kb < S_LEN; kb += KT) {
    // all waves' LDS reads from the previous tile are complete
    asm volatile("s_waitcnt lgkmcnt(0)" ::: "memory");
    __builtin_amdgcn_s_barrier();

    // ---- mask words for this tile: issued FIRST so the (younger) next-tile
    // prefetch survives the compiler's vmcnt wait on these. 16 lanes share
    // each address (broadcast, L1-served).
    unsigned mw[4] = {0u, 0u, 0u, 0u};
    if constexpr (USE_MASK) {
#pragma unroll
      for (int r = 0; r < 4; ++r)
        mw[r] = Mask[mbase + (unsigned)(r * MROW) + (unsigned)(kb >> 5)];
    }

    // ---- write the prefetched K (hi+lo) and V (hi, row-major) tile into LDS
#pragma unroll
    for (int half = 0; half < 2; ++half) {
      floatx4 kv = half ? kpre1 : kpre0;
      floatx4 vv = half ? vpre1 : vpre0;
      int row = srow + half * 16;
      unsigned short h0, h1, h2, h3, l0, l1, l2, l3;
      split_bf16(kv[0], h0, l0); split_bf16(kv[1], h1, l1);
      split_bf16(kv[2], h2, l2); split_bf16(kv[3], h3, l3);
      int kidx = row * KSTR + sc4;
      *(unsigned*)&Kh[kidx]     = (unsigned)h0 | ((unsigned)h1 << 16);
      *(unsigned*)&Kh[kidx + 2] = (unsigned)h2 | ((unsigned)h3 << 16);
      *(unsigned*)&Kl[kidx]     = (unsigned)l0 | ((unsigned)l1 << 16);
      *(unsigned*)&Kl[kidx + 2] = (unsigned)l2 | ((unsigned)l3 << 16);
      unsigned v01 = (__float_as_uint(vv[0]) >> 16) |
                     (__float_as_uint(vv[1]) & 0xFFFF0000u);
      unsigned v23 = (__float_as_uint(vv[2]) >> 16) |
                     (__float_as_uint(vv[3]) & 0xFFFF0000u);
      int vidx = row * VROW + sc4;
      *(unsigned*)&Vs[vidx]     = v01;
      *(unsigned*)&Vs[vidx + 2] = v23;
    }

    // ---- issue NEXT tile's global loads; they stay in flight across the
    // barrier below (raw s_barrier: no vmcnt drain).
    if (kb + KT < S_LEN) {
      const float* kp = kbase + (size_t)(kb + KT) * D_DIM;
      const float* vp = vbase + (size_t)(kb + KT) * D_DIM;
      kpre0 = *(const floatx4*)(kp);
      kpre1 = *(const floatx4*)(kp + 16 * D_DIM);
      vpre0 = *(const floatx4*)(vp);
      vpre1 = *(const floatx4*)(vp + 16 * D_DIM);
    }

    // ds_writes visible to the whole block; deliberately NOT draining vmcnt
    asm volatile("s_waitcnt lgkmcnt(0)" ::: "memory");
    __builtin_amdgcn_s_barrier();

    // ---- S = Q K^T (split-bf16 3-term: hh + hl + lh)
    floatx4 sc[2];
#pragma unroll
    for (int nb = 0; nb < 2; ++nb) {
      floatx4 acc = (floatx4){0.f, 0.f, 0.f, 0.f};
#pragma unroll
      for (int kc = 0; kc < 2; ++kc) {
        int bidx = (nb * 16 + m16) * KSTR + kc * 32 + quad * 8;
        short8 kbh = *(const short8*)&Kh[bidx];
        short8 kbl = *(const short8*)&Kl[bidx];
        acc = MFMA(qh[kc], kbh, acc);
        acc = MFMA(qh[kc], kbl, acc);
        acc = MFMA(ql[kc], kbh, acc);
      }
      sc[nb] = acc;
    }

    // ---- p = exp(s), per-lane l partial, dropout mask, P(hi bf16) -> LDS
#pragma unroll
    for (int nb = 0; nb < 2; ++nb)
#pragma unroll
      for (int r = 0; r < 4; ++r) {
        float pe = __expf(sc[nb][r]);
        lsum[r] += pe;
        unsigned hbits = __float_as_uint(pe) >> 16;
        if constexpr (USE_MASK) {
          // bit (nb*16+m16) of mw[r] == 1 -> drop. Shift it to bit31,
          // sign-extend, andn: 3 VALU (shift amounts are per-thread consts).
          unsigned dm = (unsigned)(((int)(mw[r] << (31 - nb * 16 - m16))) >> 31);
          hbits &= ~dm;
        } else {
          unsigned i = ibase0 + (unsigned)kb + (unsigned)(r * S_LEN) + (unsigned)(nb * 16);
          hbits &= ~drop_mask(i);
        }
        Ph[wave][(quad * 4 + r) * PSTR + nb * 16 + m16] = (unsigned short)hbits;
      }
    // Ph is wave-private; same-wave LDS RAW handled by lgkmcnt.

    // ---- O += P V  (P hi x V hi); V B-frag via conflict-free scalar u16
    short8 pa = *(const short8*)&Ph[wave][m16 * PSTR + quad * 8];
#pragma unroll
    for (int n = 0; n < 4; ++n) {
      short8 vb;
#pragma unroll
      for (int j = 0; j < 8; ++j)
        vb[j] = (short)Vs[(quad * 8 + j) * VROW + n * 16 + m16];
      o_acc[n] = MFMA(pa, vb, o_acc[n]);
    }
  }

  // ---- final l reduction over the 16 m16 lanes
#pragma unroll
  for (int off = 8; off >= 1; off >>= 1)
#pragma unroll
    for (int r = 0; r < 4; ++r)
      lsum[r] += __shfl_xor(lsum[r], off, 64);

  // ---- epilogue: out = O * (2 / l)   (2 = 1/(1-p) dropout scale)
#pragma unroll
  for (int r = 0; r < 4; ++r) {
    float scale = 2.0f / lsum[r];
#pragma unroll
    for (int n = 0; n < 4; ++n) {
      Og[head_off + (size_t)(q0 + quad * 4 + r) * D_DIM + n * 16 + m16] =
          o_acc[n][r] * scale;
    }
  }
}

extern "C" void kernel_launch(void* const* d_in, const int* in_sizes, int n_in,
                              void* d_out, int out_size, void* d_ws, size_t ws_size,
                              hipStream_t stream) {
  (void)in_sizes; (void)n_in; (void)out_size;
  const float* Q = (const float*)d_in[0];
  const float* K = (const float*)d_in[1];
  const float* V = (const float*)d_in[2];
  float* O = (float*)d_out;

  const size_t MASK_WORDS = (size_t)64 * S_LEN * MROW;   // 2^23 words = 32 MB
  if (d_ws != nullptr && ws_size >= MASK_WORDS * sizeof(unsigned)) {
    unsigned* M = (unsigned*)d_ws;
    hipLaunchKernelGGL(maskgen, dim3((unsigned)((MASK_WORDS + 511) / 512)),
                       dim3(512), 0, stream, M, (unsigned)MASK_WORDS);
    hipLaunchKernelGGL((attn_fused<true>), dim3(2048), dim3(256), 0, stream,
                       Q, K, V, O, (const unsigned*)M);
  } else {
    hipLaunchKernelGGL((attn_fused<false>), dim3(2048), dim3(256), 0, stream,
                       Q, K, V, O, (const unsigned*)nullptr);
  }
}